// Round 9
// baseline (462.288 us; speedup 1.0000x reference)
//
#include <hip/hip_runtime.h>
#include <math.h>

#define N_NODES 100000
#define N_EDGES 1600000
#define DIM 128
#define CAP 64   // per-node edge bucket capacity; deg ~ Poisson(16), P(>64) ~ 1e-12

// two-phase binned scatter (no global atomics)
#define NB1 196      // bins of 512 nodes: bin = r >> 9
#define NPB 512      // nodes per bin
#define CHUNK1 4096  // edges per bin block
#define GRID1 391    // ceil(N_EDGES / CHUNK1)
#define SLOT1 52     // per-(bin,block) bucket cap; lambda=20.9 -> 6.8 sigma (passed r3-r8)
#define LSTRIDE 197  // LDS [p][bin] stride (odd -> conflict-free flush reads)

typedef short bf16x8 __attribute__((ext_vector_type(8)));
typedef float f32x4 __attribute__((ext_vector_type(4)));

// ---- bf16 helpers (RNE pack, cheap unpack) ----
static __device__ __forceinline__ unsigned bf16rne(float f) {
    unsigned u = __float_as_uint(f);
    return (u + 0x7FFFu + ((u >> 16) & 1u)) >> 16;
}
static __device__ __forceinline__ float bflo(unsigned u) { return __uint_as_float(u << 16); }
static __device__ __forceinline__ float bfhi(unsigned u) { return __uint_as_float(u & 0xFFFF0000u); }

// ================= pb: prep || bin in ONE dispatch (independent inputs).
// Block role by blockIdx%3: {0,1}->prep (782 blocks), {2}->bin (391 blocks).
// LDS union 42 KB (prep single W buffer, hi then lo re-staged) -> 3 blocks/CU. =================

__global__ __launch_bounds__(256) void pb_k(
    const float* __restrict__ x, const float* __restrict__ Wq,
    const float* __restrict__ Wk, const float* __restrict__ Wl,
    const int* __restrict__ row, const int* __restrict__ col,
    ushort* __restrict__ xb, ushort* __restrict__ kactb,
    ushort* __restrict__ WqTh, ushort* __restrict__ WqTl,
    ushort* __restrict__ WlTh, ushort* __restrict__ WlTl,
    unsigned* __restrict__ bkt, int* __restrict__ bktc) {
    __shared__ uint4 smem4[2625];  // 42000 B union: prep{bw} | bin{lcnt,lbuf}
    int j = blockIdx.x, t = threadIdx.x;

    if (j % 3 == 2) {
        // ---------- bin role ----------
        int blk = j / 3;  // 0..390
        int* lcnt = (int*)smem4;
        unsigned* lbuf = (unsigned*)smem4 + 256;  // [p][bin], stride 197
        if (t < NB1) lcnt[t] = 0;
        __syncthreads();
        long base = (long)blk * CHUNK1;
        if (base + CHUNK1 <= N_EDGES) {
            const uint4* r4 = (const uint4*)row + (size_t)blk * 1024;
            const uint4* c4 = (const uint4*)col + (size_t)blk * 1024;
#pragma unroll
            for (int q = 0; q < 4; q++) {
                uint4 rv = r4[q * 256 + t];
                uint4 cv = c4[q * 256 + t];
                unsigned rr[4] = {rv.x, rv.y, rv.z, rv.w};
                unsigned cc[4] = {cv.x, cv.y, cv.z, cv.w};
#pragma unroll
                for (int i = 0; i < 4; i++) {
                    int b = rr[i] >> 9;
                    int p = atomicAdd(&lcnt[b], 1);
                    if (p < SLOT1) lbuf[p * LSTRIDE + b] = (cc[i] << 9) | (rr[i] & 511u);
                }
            }
        } else {
            for (int i = t; base + i < N_EDGES; i += 256) {
                unsigned r = (unsigned)row[base + i], c = (unsigned)col[base + i];
                int b = r >> 9;
                int p = atomicAdd(&lcnt[b], 1);
                if (p < SLOT1) lbuf[p * LSTRIDE + b] = (c << 9) | (r & 511u);
            }
        }
        __syncthreads();
        if (t < NB1) bktc[(size_t)blk * NB1 + t] = min(lcnt[t], SLOT1);
        int wave = t >> 6, lane = t & 63;
        for (int s = wave; s < NB1; s += 4) {
            if (lane < min(lcnt[s], SLOT1))
                bkt[((size_t)s * GRID1 + blk) * SLOT1 + lane] = lbuf[lane * LSTRIDE + s];
        }
        return;
    }

    // ---------- prep role ----------
    int p = (j / 3) * 2 + (j % 3);  // 0..781
    ushort* bw = (ushort*)smem4;    // single 128x136 W buffer (hi, then lo)

    if (p < 2) {
        const float* W = (p == 0) ? Wq : Wl;
        ushort* Th = (p == 0) ? WqTh : WlTh;
        ushort* Tl = (p == 0) ? WqTl : WlTl;
        for (int i = t; i < 16384; i += 256) {
            int k = i >> 7, n = i & 127;
            float v = W[i];
            unsigned hi = bf16rne(v);
            float lo = v - bflo(hi);
            Th[n * 128 + k] = (ushort)hi;
            Tl[n * 128 + k] = (ushort)bf16rne(lo);
        }
    }
    // stage Wk hi
    for (int i = t; i < 16384; i += 256) {
        int k = i >> 7, n = i & 127;
        bw[n * 136 + k] = (ushort)bf16rne(Wk[i]);
    }

    int wave = t >> 6, lane = t & 63;
    int ln15 = lane & 15, quad = lane >> 4;
    long base = (long)p * 128 + wave * 32;

    bf16x8 Af[2][4];
#pragma unroll
    for (int r = 0; r < 2; r++) {
        long rw = base + r * 16 + ln15;
        long rowc = rw < N_NODES ? rw : N_NODES - 1;
#pragma unroll
        for (int s = 0; s < 4; s++) {
            int ch = s * 4 + quad;  // 8-feat chunk index (0..15)
            const float4* xp = (const float4*)(x + rowc * 128 + ch * 8);
            float4 u0 = xp[0], u1 = xp[1];
            bf16x8 f;
            f[0] = (short)bf16rne(u0.x); f[1] = (short)bf16rne(u0.y);
            f[2] = (short)bf16rne(u0.z); f[3] = (short)bf16rne(u0.w);
            f[4] = (short)bf16rne(u1.x); f[5] = (short)bf16rne(u1.y);
            f[6] = (short)bf16rne(u1.z); f[7] = (short)bf16rne(u1.w);
            Af[r][s] = f;
            if (rw < N_NODES) *(bf16x8*)(xb + rw * 128 + ch * 8) = f;
        }
    }
    f32x4 acc[2][8];
#pragma unroll
    for (int r = 0; r < 2; r++)
#pragma unroll
        for (int t8 = 0; t8 < 8; t8++) acc[r][t8] = (f32x4){0.f, 0.f, 0.f, 0.f};

    __syncthreads();
    // MFMA phase 0 (hi)
#pragma unroll
    for (int s = 0; s < 4; s++) {
#pragma unroll
        for (int t8 = 0; t8 < 8; t8++) {
            bf16x8 b = *(const bf16x8*)(bw + (t8 * 16 + ln15) * 136 + (s * 4 + quad) * 8);
            acc[0][t8] = __builtin_amdgcn_mfma_f32_16x16x32_bf16(Af[0][s], b, acc[0][t8], 0, 0, 0);
            acc[1][t8] = __builtin_amdgcn_mfma_f32_16x16x32_bf16(Af[1][s], b, acc[1][t8], 0, 0, 0);
        }
    }
    __syncthreads();
    // re-stage Wk lo
    for (int i = t; i < 16384; i += 256) {
        int k = i >> 7, n = i & 127;
        float v = Wk[i];
        unsigned hi = bf16rne(v);
        float lo = v - bflo(hi);
        bw[n * 136 + k] = (ushort)bf16rne(lo);
    }
    __syncthreads();
    // MFMA phase 1 (lo)
#pragma unroll
    for (int s = 0; s < 4; s++) {
#pragma unroll
        for (int t8 = 0; t8 < 8; t8++) {
            bf16x8 b = *(const bf16x8*)(bw + (t8 * 16 + ln15) * 136 + (s * 4 + quad) * 8);
            acc[0][t8] = __builtin_amdgcn_mfma_f32_16x16x32_bf16(Af[0][s], b, acc[0][t8], 0, 0, 0);
            acc[1][t8] = __builtin_amdgcn_mfma_f32_16x16x32_bf16(Af[1][s], b, acc[1][t8], 0, 0, 0);
        }
    }
#pragma unroll
    for (int r = 0; r < 2; r++) {
#pragma unroll
        for (int reg = 0; reg < 4; reg++) {
            long node = base + r * 16 + quad * 4 + reg;
            if (node < N_NODES) {
#pragma unroll
                for (int t8 = 0; t8 < 8; t8++) {
                    float v = acc[r][t8][reg];
                    v = v > 0.f ? v : 0.2f * v;
                    kactb[node * 128 + t8 * 16 + ln15] = (ushort)bf16rne(v);
                }
            }
        }
    }
}

// ================= pass 0b: one block (16 waves) per 512-node bin =================

__global__ __launch_bounds__(1024) void build_k(const int* __restrict__ bktc,
                                                const unsigned* __restrict__ bkt,
                                                int* __restrict__ cur,
                                                int* __restrict__ scol) {
    __shared__ int lcur[NPB];
    __shared__ int lc[GRID1];
    int b = blockIdx.x, t = threadIdx.x;
    if (t < NPB) lcur[t] = 0;
    if (t < GRID1) lc[t] = bktc[(size_t)t * NB1 + b];
    __syncthreads();
    int wave = t >> 6, lane = t & 63;
    const unsigned* D = bkt + (size_t)b * GRID1 * SLOT1;
    for (int s = wave; s < GRID1; s += 16) {
        if (lane < lc[s]) {
            unsigned v = D[(size_t)s * SLOT1 + lane];
            int rl = (int)(v & 511u);
            int c = (int)(v >> 9);
            int p = atomicAdd(&lcur[rl], 1);
            if (p < CAP) scol[((size_t)b * NPB + rl) * CAP + p] = c;
        }
    }
    __syncthreads();
    if (t < NPB) {
        int node = b * NPB + t;
        if (node < N_NODES) cur[node] = lcur[t];
    }
}

// ================= xq: fused x_agg gather + 16x128x128 MFMA GEMM.
// 256 thr / 16 nodes per block; each WAVE processes its 4 nodes SEQUENTIALLY
// with all 64 lanes (4 edges in flight, 16 lanes/row) -> wave time ~ sum of
// degrees (balanced), not max. qx built with FULL-LINE uint4 stores. =================

__global__ __launch_bounds__(256) void xq_k(const uint4* __restrict__ xb4,
                                            const int* __restrict__ cur,
                                            const int* __restrict__ scol,
                                            const ushort* __restrict__ BTh,
                                            const ushort* __restrict__ BTl,
                                            uint4* __restrict__ qx4) {
    __shared__ ushort lxa[16][136];  // pad 136 -> conflict-free frag reads
    __shared__ ushort lq[16][136];   // q result staging
    int t = threadIdx.x;
    int wave = t >> 6, lane = t & 63;
    int e = lane >> 4;   // edge subgroup 0..3
    int gl = lane & 15;  // feature chunk
    long blkbase = (long)blockIdx.x * 16;  // grid exact: 6250*16 = 100000

#pragma unroll
    for (int i = 0; i < 4; i++) {
        int li = wave * 4 + i;           // local node 0..15
        long node = blkbase + li;
        int d = min(cur[node], CAP);
        int cb = (lane < d) ? scol[node * CAP + lane] : 0;
        float a0 = 0.f, a1 = 0.f, a2 = 0.f, a3 = 0.f;
        float a4 = 0.f, a5 = 0.f, a6 = 0.f, a7 = 0.f;
        int k = 0;
        for (; k + 8 <= d; k += 8) {
            int c0 = __shfl(cb, k + e, 64);
            int c1 = __shfl(cb, k + 4 + e, 64);
            uint4 u0 = xb4[(size_t)c0 * 16 + gl];
            uint4 u1 = xb4[(size_t)c1 * 16 + gl];
            a0 += bflo(u0.x); a1 += bfhi(u0.x); a2 += bflo(u0.y); a3 += bfhi(u0.y);
            a4 += bflo(u0.z); a5 += bfhi(u0.z); a6 += bflo(u0.w); a7 += bfhi(u0.w);
            a0 += bflo(u1.x); a1 += bfhi(u1.x); a2 += bflo(u1.y); a3 += bfhi(u1.y);
            a4 += bflo(u1.z); a5 += bfhi(u1.z); a6 += bflo(u1.w); a7 += bfhi(u1.w);
        }
        for (; k < d; k += 4) {
            int c = __shfl(cb, k + e, 64);
            uint4 u = xb4[(size_t)c * 16 + gl];
            if (k + e < d) {
                a0 += bflo(u.x); a1 += bfhi(u.x); a2 += bflo(u.y); a3 += bfhi(u.y);
                a4 += bflo(u.z); a5 += bfhi(u.z); a6 += bflo(u.w); a7 += bfhi(u.w);
            }
        }
        // reduce across the 4 edge subgroups (lanes l, l^16, l^32, l^48)
        a0 += __shfl_xor(a0, 16, 64); a1 += __shfl_xor(a1, 16, 64);
        a2 += __shfl_xor(a2, 16, 64); a3 += __shfl_xor(a3, 16, 64);
        a4 += __shfl_xor(a4, 16, 64); a5 += __shfl_xor(a5, 16, 64);
        a6 += __shfl_xor(a6, 16, 64); a7 += __shfl_xor(a7, 16, 64);
        a0 += __shfl_xor(a0, 32, 64); a1 += __shfl_xor(a1, 32, 64);
        a2 += __shfl_xor(a2, 32, 64); a3 += __shfl_xor(a3, 32, 64);
        a4 += __shfl_xor(a4, 32, 64); a5 += __shfl_xor(a5, 32, 64);
        a6 += __shfl_xor(a6, 32, 64); a7 += __shfl_xor(a7, 32, 64);
        if (e == 0) {
            uint4 o;
            o.x = bf16rne(a0) | (bf16rne(a1) << 16);
            o.y = bf16rne(a2) | (bf16rne(a3) << 16);
            o.z = bf16rne(a4) | (bf16rne(a5) << 16);
            o.w = bf16rne(a6) | (bf16rne(a7) << 16);
            *(uint4*)&lxa[li][gl * 8] = o;
        }
    }
    __syncthreads();

    // GEMM: 16x128 out, 8 (16x16) tiles, 4 waves x 2 tiles; q -> lq
    int ln15 = lane & 15, quad = (lane >> 4) & 3;
    const bf16x8* Bh8 = (const bf16x8*)BTh;
    const bf16x8* Bl8 = (const bf16x8*)BTl;
    bf16x8 af[4];
#pragma unroll
    for (int s = 0; s < 4; s++)
        af[s] = *(const bf16x8*)&lxa[ln15][(s * 4 + quad) * 8];
#pragma unroll
    for (int ti = 0; ti < 2; ti++) {
        int ct = wave * 2 + ti;  // 0..7
        f32x4 acc = (f32x4){0.f, 0.f, 0.f, 0.f};
#pragma unroll
        for (int phase = 0; phase < 2; phase++) {
            const bf16x8* B8 = phase ? Bl8 : Bh8;
#pragma unroll
            for (int s = 0; s < 4; s++)
                acc = __builtin_amdgcn_mfma_f32_16x16x32_bf16(
                    af[s], B8[(ct * 16 + ln15) * 16 + s * 4 + quad], acc, 0, 0, 0);
        }
#pragma unroll
        for (int reg = 0; reg < 4; reg++)
            lq[quad * 4 + reg][ct * 16 + ln15] = (ushort)bf16rne(acc[reg]);
    }
    __syncthreads();

    // combine+store: full-line qx writes. chunk c of node n (16B):
    // {q[4c..4c+3], x[4c..4c+3]}; 512 chunks/block, coalesced
    const uint2* xb2 = (const uint2*)xb4;
#pragma unroll
    for (int i = 0; i < 2; i++) {
        int idx = i * 256 + t;
        int g = idx >> 5, c = idx & 31;
        long n2 = blkbase + g;
        uint2 q2 = *(const uint2*)&lq[g][c * 4];
        uint2 x2 = xb2[n2 * 32 + c];
        qx4[n2 * 32 + c] = make_uint4(q2.x, q2.y, x2.x, x2.y);
    }
}

// ================= pass B: attention, ONE NODE PER 64-LANE WAVE.
// Halves process edges k / k+1 of the same node -> one reduce+exp serves 2
// edges; no cross-node divergence; no barrier. No-max softmax (f32 headroom). =================

__global__ __launch_bounds__(256) void attn_k(const uint2* __restrict__ kactb,
                                              const uint4* __restrict__ qx4,
                                              const int* __restrict__ cur,
                                              const int* __restrict__ scol,
                                              uint2* __restrict__ xwb,
                                              float* __restrict__ sumw) {
    long g = (blockIdx.x * 256 + threadIdx.x) >> 6;  // node id (grid exact: 25000*4)
    int lane = threadIdx.x & 63;
    int l31 = lane & 31;
    int h = lane >> 5;  // half: edge parity
    int d = min(cur[g], CAP);
    uint2 ku = kactb[(size_t)g * 32 + l31];
    const float scale = 0.08838834764831845f;  // 1/sqrt(128)
    float k0 = bflo(ku.x) * scale, k1 = bfhi(ku.x) * scale;
    float k2 = bflo(ku.y) * scale, k3 = bfhi(ku.y) * scale;

    int cb = (lane < d) ? scol[g * CAP + lane] : 0;  // whole bucket, one load
    float S = 0.f;
    float a0 = 0.f, a1 = 0.f, a2 = 0.f, a3 = 0.f;
    int k = 0;
    for (; k + 8 <= d; k += 8) {
        int c0 = __shfl(cb, k + h, 64);
        int c1 = __shfl(cb, k + 2 + h, 64);
        int c2 = __shfl(cb, k + 4 + h, 64);
        int c3 = __shfl(cb, k + 6 + h, 64);
        uint4 u0 = qx4[(size_t)c0 * 32 + l31];
        uint4 u1 = qx4[(size_t)c1 * 32 + l31];
        uint4 u2 = qx4[(size_t)c2 * 32 + l31];
        uint4 u3 = qx4[(size_t)c3 * 32 + l31];
        float p0 = k0 * bflo(u0.x) + k1 * bfhi(u0.x) + k2 * bflo(u0.y) + k3 * bfhi(u0.y);
        float p1 = k0 * bflo(u1.x) + k1 * bfhi(u1.x) + k2 * bflo(u1.y) + k3 * bfhi(u1.y);
        float p2 = k0 * bflo(u2.x) + k1 * bfhi(u2.x) + k2 * bflo(u2.y) + k3 * bfhi(u2.y);
        float p3 = k0 * bflo(u3.x) + k1 * bfhi(u3.x) + k2 * bflo(u3.y) + k3 * bfhi(u3.y);
#pragma unroll
        for (int off = 16; off > 0; off >>= 1) {
            p0 += __shfl_xor(p0, off, 32); p1 += __shfl_xor(p1, off, 32);
            p2 += __shfl_xor(p2, off, 32); p3 += __shfl_xor(p3, off, 32);
        }
        float e0 = __expf(p0), e1 = __expf(p1);
        float e2 = __expf(p2), e3 = __expf(p3);
        S += (e0 + e1) + (e2 + e3);
        a0 += e0 * bflo(u0.z) + e1 * bflo(u1.z) + e2 * bflo(u2.z) + e3 * bflo(u3.z);
        a1 += e0 * bfhi(u0.z) + e1 * bfhi(u1.z) + e2 * bfhi(u2.z) + e3 * bfhi(u3.z);
        a2 += e0 * bflo(u0.w) + e1 * bflo(u1.w) + e2 * bflo(u2.w) + e3 * bflo(u3.w);
        a3 += e0 * bfhi(u0.w) + e1 * bfhi(u1.w) + e2 * bfhi(u2.w) + e3 * bfhi(u3.w);
    }
    for (; k + 2 <= d; k += 2) {
        int c = __shfl(cb, k + h, 64);
        uint4 u = qx4[(size_t)c * 32 + l31];
        float p = k0 * bflo(u.x) + k1 * bfhi(u.x) + k2 * bflo(u.y) + k3 * bfhi(u.y);
#pragma unroll
        for (int off = 16; off > 0; off >>= 1) p += __shfl_xor(p, off, 32);
        float e0 = __expf(p);
        S += e0;
        a0 += e0 * bflo(u.z);
        a1 += e0 * bfhi(u.z);
        a2 += e0 * bflo(u.w);
        a3 += e0 * bfhi(u.w);
    }
    if (k < d) {  // last odd edge: both halves compute, half 0 accumulates
        int c = __shfl(cb, k, 64);
        uint4 u = qx4[(size_t)c * 32 + l31];
        float p = k0 * bflo(u.x) + k1 * bfhi(u.x) + k2 * bflo(u.y) + k3 * bfhi(u.y);
#pragma unroll
        for (int off = 16; off > 0; off >>= 1) p += __shfl_xor(p, off, 32);
        float e0 = __expf(p);
        if (h == 0) {
            S += e0;
            a0 += e0 * bflo(u.z);
            a1 += e0 * bfhi(u.z);
            a2 += e0 * bflo(u.w);
            a3 += e0 * bfhi(u.w);
        }
    }
    // combine the two halves
    S += __shfl_xor(S, 32, 64);
    a0 += __shfl_xor(a0, 32, 64);
    a1 += __shfl_xor(a1, 32, 64);
    a2 += __shfl_xor(a2, 32, 64);
    a3 += __shfl_xor(a3, 32, 64);
    float inv = 1.f / (S + 1e-8f);
    if (h == 0) {
        uint2 o;
        o.x = bf16rne(a0 * inv) | (bf16rne(a1 * inv) << 16);
        o.y = bf16rne(a2 * inv) | (bf16rne(a3 * inv) << 16);
        xwb[(size_t)g * 32 + l31] = o;
        if (l31 == 0) sumw[g] = S * inv;  // sum(alpha) for exact bias term
    }
}

// ================= final MFMA GEMM: out = lrelu(xw @ Wl + sumw*b), f32 out =================

__global__ __launch_bounds__(256) void fin_k(const ushort* __restrict__ Ab,
                                             const ushort* __restrict__ BTh,
                                             const ushort* __restrict__ BTl,
                                             const float* __restrict__ bl,
                                             const float* __restrict__ sumw,
                                             float* __restrict__ out) {
    int tid = threadIdx.x;
    int wave = tid >> 6, lane = tid & 63;
    int ln15 = lane & 15, quad = (lane >> 4) & 3;
    long base = (long)blockIdx.x * 128 + wave * 32;

    const bf16x8* A8 = (const bf16x8*)Ab;
    const bf16x8* Bh8 = (const bf16x8*)BTh;
    const bf16x8* Bl8 = (const bf16x8*)BTl;

    bf16x8 Af[2][4];
#pragma unroll
    for (int r = 0; r < 2; r++) {
        long row = base + r * 16 + ln15;
#pragma unroll
        for (int s = 0; s < 4; s++) Af[r][s] = A8[row * 16 + s * 4 + quad];
    }
    float blv[8];
#pragma unroll
    for (int t = 0; t < 8; t++) blv[t] = bl[t * 16 + ln15];

    f32x4 acc[2][8];
#pragma unroll
    for (int r = 0; r < 2; r++)
#pragma unroll
        for (int t = 0; t < 8; t++) acc[r][t] = (f32x4){0.f, 0.f, 0.f, 0.f};

#pragma unroll
    for (int phase = 0; phase < 2; phase++) {
        const bf16x8* B8 = phase ? Bl8 : Bh8;
#pragma unroll
        for (int s = 0; s < 4; s++) {
#pragma unroll
            for (int t = 0; t < 8; t++) {
                bf16x8 b = B8[(t * 16 + ln15) * 16 + s * 4 + quad];
                acc[0][t] = __builtin_amdgcn_mfma_f32_16x16x32_bf16(Af[0][s], b, acc[0][t], 0, 0, 0);
                acc[1][t] = __builtin_amdgcn_mfma_f32_16x16x32_bf16(Af[1][s], b, acc[1][t], 0, 0, 0);
            }
        }
    }
#pragma unroll
    for (int r = 0; r < 2; r++) {
#pragma unroll
        for (int reg = 0; reg < 4; reg++) {
            long node = base + r * 16 + quad * 4 + reg;
            if (node < N_NODES) {
                float sw = sumw[node];
#pragma unroll
                for (int t = 0; t < 8; t++) {
                    float v = acc[r][t][reg] + sw * blv[t];
                    v = v > 0.f ? v : 0.2f * v;
                    out[node * 128 + t * 16 + ln15] = v;
                }
            }
        }
    }
}

// ================= launch =================

extern "C" void kernel_launch(void* const* d_in, const int* in_sizes, int n_in,
                              void* d_out, int out_size, void* d_ws, size_t ws_size,
                              hipStream_t stream) {
    const float* x  = (const float*)d_in[0];
    const int* row  = (const int*)d_in[1];
    const int* col  = row + N_EDGES;
    const float* Wq = (const float*)d_in[2];
    const float* Wk = (const float*)d_in[3];
    // d_in[4] = W_v: unused
    const float* Wl = (const float*)d_in[5];
    const float* bl = (const float*)d_in[6];
    float* out = (float*)d_out;

    // workspace carve (~171 MB). fin_k A-loads overread <=96 rows past xwb
    // (lands in wbuf, valid memory).
    ushort* xb    = (ushort*)d_ws;                        // N*128 bf16 (25.6 MB)
    ushort* qx    = xb + (size_t)N_NODES * DIM;           // N*256 bf16 interleaved q|x (51.2 MB)
    ushort* kactb = qx + (size_t)N_NODES * 256;           // 25.6 MB
    ushort* xwb   = kactb + (size_t)N_NODES * DIM;        // 25.6 MB
    ushort* wbuf  = xwb + (size_t)N_NODES * DIM;          // 4*16384 bf16
    ushort* WqTh = wbuf,             *WqTl = wbuf + 16384;
    ushort* WlTh = wbuf + 2 * 16384, *WlTl = wbuf + 3 * 16384;
    float* sumw = (float*)(wbuf + 4 * 16384);             // N f32
    int* cur  = (int*)(sumw + N_NODES);                   // N (degrees, by build_k)
    int* scol = cur + N_NODES;                            // N*CAP (25.6 MB)
    unsigned* bkt = (unsigned*)(scol + (size_t)N_NODES * CAP);  // 15.9 MB
    int* bktc = (int*)(bkt + (size_t)NB1 * GRID1 * SLOT1);      // 306 KB

    pb_k<<<1173, 256, 0, stream>>>(x, Wq, Wk, Wl, row, col, xb, kactb,
                                   WqTh, WqTl, WlTh, WlTl, bkt, bktc);
    build_k<<<NB1, 1024, 0, stream>>>(bktc, bkt, cur, scol);
    xq_k<<<N_NODES / 16, 256, 0, stream>>>((const uint4*)xb, cur, scol,
                                           WqTh, WqTl, (uint4*)qx);
    attn_k<<<N_NODES / 4, 256, 0, stream>>>((const uint2*)kactb, (const uint4*)qx,
                                            cur, scol, (uint2*)xwb, sumw);
    fin_k<<<(N_NODES + 127) / 128, 256, 0, stream>>>(xwb, WlTh, WlTl, bl, sumw, out);
}

// Round 10
// 450.236 us; speedup vs baseline: 1.0268x; 1.0268x over previous
//
#include <hip/hip_runtime.h>
#include <math.h>

#define N_NODES 100000
#define N_EDGES 1600000
#define DIM 128
#define CAP 64   // per-node edge bucket capacity; deg ~ Poisson(16), P(>64) ~ 1e-12

// two-phase binned scatter (no global atomics)
#define NB1 196      // bins of 512 nodes: bin = r >> 9
#define NPB 512      // nodes per bin
#define CHUNK1 4096  // edges per bin block
#define GRID1 391    // ceil(N_EDGES / CHUNK1)
#define SLOT1 52     // per-(bin,block) bucket cap; lambda=20.9 -> 6.8 sigma (passed r3-r9)
#define LSTRIDE 197  // LDS [p][bin] stride (odd -> conflict-free flush reads)

typedef short bf16x8 __attribute__((ext_vector_type(8)));
typedef float f32x4 __attribute__((ext_vector_type(4)));

// ---- bf16 helpers (RNE pack, cheap unpack) ----
static __device__ __forceinline__ unsigned bf16rne(float f) {
    unsigned u = __float_as_uint(f);
    return (u + 0x7FFFu + ((u >> 16) & 1u)) >> 16;
}
static __device__ __forceinline__ float bflo(unsigned u) { return __uint_as_float(u << 16); }
static __device__ __forceinline__ float bfhi(unsigned u) { return __uint_as_float(u & 0xFFFF0000u); }

// ================= pb: prep || bin in ONE dispatch.
// prep: xb = bf16(x); k_act = lrelu(x@Wk) (GEMM1, hi/lo);
//       kq = k_act @ Wq^T (GEMM2, hi/lo) -- score(g,c) = kq[g].xagg[c],
//       algebraic identity k.(xagg@Wq) = (k@Wq^T).xagg, so q is never built.
// bin: LDS-binned edge scatter, zero global atomics. =================

__global__ __launch_bounds__(256) void pb_k(
    const float* __restrict__ x, const float* __restrict__ Wq,
    const float* __restrict__ Wk, const float* __restrict__ Wl,
    const int* __restrict__ row, const int* __restrict__ col,
    ushort* __restrict__ xb, ushort* __restrict__ kq,
    ushort* __restrict__ WlTh, ushort* __restrict__ WlTl,
    unsigned* __restrict__ bkt, int* __restrict__ bktc) {
    __shared__ uint4 smem4[4352];  // 69632 B union: prep{b1,b2} | bin{lcnt,lbuf}
    int j = blockIdx.x, t = threadIdx.x;

    if (j % 3 == 2) {
        // ---------- bin role ----------
        int blk = j / 3;  // 0..390
        int* lcnt = (int*)smem4;
        unsigned* lbuf = (unsigned*)smem4 + 256;  // [p][bin], stride 197
        if (t < NB1) lcnt[t] = 0;
        __syncthreads();
        long base = (long)blk * CHUNK1;
        if (base + CHUNK1 <= N_EDGES) {
            const uint4* r4 = (const uint4*)row + (size_t)blk * 1024;
            const uint4* c4 = (const uint4*)col + (size_t)blk * 1024;
#pragma unroll
            for (int q = 0; q < 4; q++) {
                uint4 rv = r4[q * 256 + t];
                uint4 cv = c4[q * 256 + t];
                unsigned rr[4] = {rv.x, rv.y, rv.z, rv.w};
                unsigned cc[4] = {cv.x, cv.y, cv.z, cv.w};
#pragma unroll
                for (int i = 0; i < 4; i++) {
                    int b = rr[i] >> 9;
                    int p = atomicAdd(&lcnt[b], 1);
                    if (p < SLOT1) lbuf[p * LSTRIDE + b] = (cc[i] << 9) | (rr[i] & 511u);
                }
            }
        } else {
            for (int i = t; base + i < N_EDGES; i += 256) {
                unsigned r = (unsigned)row[base + i], c = (unsigned)col[base + i];
                int b = r >> 9;
                int p = atomicAdd(&lcnt[b], 1);
                if (p < SLOT1) lbuf[p * LSTRIDE + b] = (c << 9) | (r & 511u);
            }
        }
        __syncthreads();
        if (t < NB1) bktc[(size_t)blk * NB1 + t] = min(lcnt[t], SLOT1);
        int wave = t >> 6, lane = t & 63;
        for (int s = wave; s < NB1; s += 4) {
            if (lane < min(lcnt[s], SLOT1))
                bkt[((size_t)s * GRID1 + blk) * SLOT1 + lane] = lbuf[lane * LSTRIDE + s];
        }
        return;
    }

    // ---------- prep role ----------
    int p = (j / 3) * 2 + (j % 3);  // 0..781
    ushort* b1 = (ushort*)smem4;    // 128x136: k_act staging (GEMM2 A)
    ushort* b2 = b1 + 17408;        // 128x136: W staging (hi then lo, Wk then Wq)

    if (p == 0) {
        // Wl split for fin (transposed layout [out][in])
        for (int i = t; i < 16384; i += 256) {
            int k = i >> 7, n = i & 127;
            float v = Wl[i];
            unsigned hi = bf16rne(v);
            WlTh[n * 128 + k] = (ushort)hi;
            WlTl[n * 128 + k] = (ushort)bf16rne(v - bflo(hi));
        }
    }
    // stage Wk hi (transposed: [out n][in k])
    for (int i = t; i < 16384; i += 256) {
        int k = i >> 7, n = i & 127;
        b2[n * 136 + k] = (ushort)bf16rne(Wk[i]);
    }

    int wave = t >> 6, lane = t & 63;
    int ln15 = lane & 15, quad = lane >> 4;
    long base = (long)p * 128 + wave * 32;

    bf16x8 Af[2][4];
#pragma unroll
    for (int r = 0; r < 2; r++) {
        long rw = base + r * 16 + ln15;
        long rowc = rw < N_NODES ? rw : N_NODES - 1;
#pragma unroll
        for (int s = 0; s < 4; s++) {
            int ch = s * 4 + quad;  // 8-feat chunk index (0..15)
            const float4* xp = (const float4*)(x + rowc * 128 + ch * 8);
            float4 u0 = xp[0], u1 = xp[1];
            bf16x8 f;
            f[0] = (short)bf16rne(u0.x); f[1] = (short)bf16rne(u0.y);
            f[2] = (short)bf16rne(u0.z); f[3] = (short)bf16rne(u0.w);
            f[4] = (short)bf16rne(u1.x); f[5] = (short)bf16rne(u1.y);
            f[6] = (short)bf16rne(u1.z); f[7] = (short)bf16rne(u1.w);
            Af[r][s] = f;
            if (rw < N_NODES) *(bf16x8*)(xb + rw * 128 + ch * 8) = f;
        }
    }
    f32x4 acc[2][8];
#pragma unroll
    for (int r = 0; r < 2; r++)
#pragma unroll
        for (int t8 = 0; t8 < 8; t8++) acc[r][t8] = (f32x4){0.f, 0.f, 0.f, 0.f};

    __syncthreads();
    // GEMM1 hi
#pragma unroll
    for (int s = 0; s < 4; s++) {
#pragma unroll
        for (int t8 = 0; t8 < 8; t8++) {
            bf16x8 b = *(const bf16x8*)(b2 + (t8 * 16 + ln15) * 136 + (s * 4 + quad) * 8);
            acc[0][t8] = __builtin_amdgcn_mfma_f32_16x16x32_bf16(Af[0][s], b, acc[0][t8], 0, 0, 0);
            acc[1][t8] = __builtin_amdgcn_mfma_f32_16x16x32_bf16(Af[1][s], b, acc[1][t8], 0, 0, 0);
        }
    }
    __syncthreads();
    // restage Wk lo
    for (int i = t; i < 16384; i += 256) {
        int k = i >> 7, n = i & 127;
        float v = Wk[i];
        unsigned hi = bf16rne(v);
        b2[n * 136 + k] = (ushort)bf16rne(v - bflo(hi));
    }
    __syncthreads();
    // GEMM1 lo
#pragma unroll
    for (int s = 0; s < 4; s++) {
#pragma unroll
        for (int t8 = 0; t8 < 8; t8++) {
            bf16x8 b = *(const bf16x8*)(b2 + (t8 * 16 + ln15) * 136 + (s * 4 + quad) * 8);
            acc[0][t8] = __builtin_amdgcn_mfma_f32_16x16x32_bf16(Af[0][s], b, acc[0][t8], 0, 0, 0);
            acc[1][t8] = __builtin_amdgcn_mfma_f32_16x16x32_bf16(Af[1][s], b, acc[1][t8], 0, 0, 0);
        }
    }
    // k_act = lrelu(acc) -> b1 (bf16, [local node][feat])
#pragma unroll
    for (int r = 0; r < 2; r++) {
#pragma unroll
        for (int reg = 0; reg < 4; reg++) {
            int rl = wave * 32 + r * 16 + quad * 4 + reg;  // 0..127
#pragma unroll
            for (int t8 = 0; t8 < 8; t8++) {
                float v = acc[r][t8][reg];
                v = v > 0.f ? v : 0.2f * v;
                b1[rl * 136 + t8 * 16 + ln15] = (ushort)bf16rne(v);
            }
        }
    }
    __syncthreads();
    // stage Wq hi DIRECT order: B-layout [out j][in f] = Wq[j*128+f] (no transpose)
    for (int i = t; i < 16384; i += 256) {
        b2[(i >> 7) * 136 + (i & 127)] = (ushort)bf16rne(Wq[i]);
    }
    __syncthreads();
#pragma unroll
    for (int r = 0; r < 2; r++)
#pragma unroll
        for (int t8 = 0; t8 < 8; t8++) acc[r][t8] = (f32x4){0.f, 0.f, 0.f, 0.f};
    // GEMM2 hi: kq = k_act @ Wq^T
#pragma unroll
    for (int r = 0; r < 2; r++) {
        bf16x8 af[4];
#pragma unroll
        for (int s = 0; s < 4; s++)
            af[s] = *(const bf16x8*)(b1 + (wave * 32 + r * 16 + ln15) * 136 + (s * 4 + quad) * 8);
#pragma unroll
        for (int s = 0; s < 4; s++) {
#pragma unroll
            for (int t8 = 0; t8 < 8; t8++) {
                bf16x8 b = *(const bf16x8*)(b2 + (t8 * 16 + ln15) * 136 + (s * 4 + quad) * 8);
                acc[r][t8] = __builtin_amdgcn_mfma_f32_16x16x32_bf16(af[s], b, acc[r][t8], 0, 0, 0);
            }
        }
    }
    __syncthreads();
    // restage Wq lo
    for (int i = t; i < 16384; i += 256) {
        float v = Wq[i];
        unsigned hi = bf16rne(v);
        b2[(i >> 7) * 136 + (i & 127)] = (ushort)bf16rne(v - bflo(hi));
    }
    __syncthreads();
    // GEMM2 lo
#pragma unroll
    for (int r = 0; r < 2; r++) {
        bf16x8 af[4];
#pragma unroll
        for (int s = 0; s < 4; s++)
            af[s] = *(const bf16x8*)(b1 + (wave * 32 + r * 16 + ln15) * 136 + (s * 4 + quad) * 8);
#pragma unroll
        for (int s = 0; s < 4; s++) {
#pragma unroll
            for (int t8 = 0; t8 < 8; t8++) {
                bf16x8 b = *(const bf16x8*)(b2 + (t8 * 16 + ln15) * 136 + (s * 4 + quad) * 8);
                acc[r][t8] = __builtin_amdgcn_mfma_f32_16x16x32_bf16(af[s], b, acc[r][t8], 0, 0, 0);
            }
        }
    }
    // store kq
#pragma unroll
    for (int r = 0; r < 2; r++) {
#pragma unroll
        for (int reg = 0; reg < 4; reg++) {
            long node = base + r * 16 + quad * 4 + reg;
            if (node < N_NODES) {
#pragma unroll
                for (int t8 = 0; t8 < 8; t8++)
                    kq[node * 128 + t8 * 16 + ln15] = (ushort)bf16rne(acc[r][t8][reg]);
            }
        }
    }
}

// ================= pass 0b: one block (16 waves) per 512-node bin =================

__global__ __launch_bounds__(1024) void build_k(const int* __restrict__ bktc,
                                                const unsigned* __restrict__ bkt,
                                                int* __restrict__ cur,
                                                int* __restrict__ scol) {
    __shared__ int lcur[NPB];
    __shared__ int lc[GRID1];
    int b = blockIdx.x, t = threadIdx.x;
    if (t < NPB) lcur[t] = 0;
    if (t < GRID1) lc[t] = bktc[(size_t)t * NB1 + b];
    __syncthreads();
    int wave = t >> 6, lane = t & 63;
    const unsigned* D = bkt + (size_t)b * GRID1 * SLOT1;
    for (int s = wave; s < GRID1; s += 16) {
        if (lane < lc[s]) {
            unsigned v = D[(size_t)s * SLOT1 + lane];
            int rl = (int)(v & 511u);
            int c = (int)(v >> 9);
            int p = atomicAdd(&lcur[rl], 1);
            if (p < CAP) scol[((size_t)b * NPB + rl) * CAP + p] = c;
        }
    }
    __syncthreads();
    if (t < NPB) {
        int node = b * NPB + t;
        if (node < N_NODES) cur[node] = lcur[t];
    }
}

// ================= xa: x_agg gather (16 lanes/node, 4-deep ILP, NO barrier,
// ================= no LDS, no GEMM) + full-line combined ax=[xagg|x] writes =================

__global__ __launch_bounds__(256) void xa_k(const uint4* __restrict__ xb4,
                                            const int* __restrict__ cur,
                                            const int* __restrict__ scol,
                                            uint4* __restrict__ ax4) {
    int g = (blockIdx.x * 256 + threadIdx.x) >> 4;  // node id (grid exact)
    int gl = threadIdx.x & 15;
    int d = min(cur[g], CAP);
    float a0 = 0.f, a1 = 0.f, a2 = 0.f, a3 = 0.f;
    float a4 = 0.f, a5 = 0.f, a6 = 0.f, a7 = 0.f;
    for (int j = 0; j < d; j += 16) {
        int cb = (j + gl < d) ? scol[(size_t)g * CAP + j + gl] : 0;
        int lim = min(16, d - j);
        int k = 0;
        for (; k + 4 <= lim; k += 4) {
            int c0 = __shfl(cb, k, 16),     c1 = __shfl(cb, k + 1, 16);
            int c2 = __shfl(cb, k + 2, 16), c3 = __shfl(cb, k + 3, 16);
            uint4 u0 = xb4[(size_t)c0 * 16 + gl];
            uint4 u1 = xb4[(size_t)c1 * 16 + gl];
            uint4 u2 = xb4[(size_t)c2 * 16 + gl];
            uint4 u3 = xb4[(size_t)c3 * 16 + gl];
            a0 += bflo(u0.x); a1 += bfhi(u0.x); a2 += bflo(u0.y); a3 += bfhi(u0.y);
            a4 += bflo(u0.z); a5 += bfhi(u0.z); a6 += bflo(u0.w); a7 += bfhi(u0.w);
            a0 += bflo(u1.x); a1 += bfhi(u1.x); a2 += bflo(u1.y); a3 += bfhi(u1.y);
            a4 += bflo(u1.z); a5 += bfhi(u1.z); a6 += bflo(u1.w); a7 += bfhi(u1.w);
            a0 += bflo(u2.x); a1 += bfhi(u2.x); a2 += bflo(u2.y); a3 += bfhi(u2.y);
            a4 += bflo(u2.z); a5 += bfhi(u2.z); a6 += bflo(u2.w); a7 += bfhi(u2.w);
            a0 += bflo(u3.x); a1 += bfhi(u3.x); a2 += bflo(u3.y); a3 += bfhi(u3.y);
            a4 += bflo(u3.z); a5 += bfhi(u3.z); a6 += bflo(u3.w); a7 += bfhi(u3.w);
        }
        for (; k < lim; k++) {
            int c = __shfl(cb, k, 16);
            uint4 u = xb4[(size_t)c * 16 + gl];
            a0 += bflo(u.x); a1 += bfhi(u.x); a2 += bflo(u.y); a3 += bfhi(u.y);
            a4 += bflo(u.z); a5 += bfhi(u.z); a6 += bflo(u.w); a7 += bfhi(u.w);
        }
    }
    uint4 o;
    o.x = bf16rne(a0) | (bf16rne(a1) << 16);
    o.y = bf16rne(a2) | (bf16rne(a3) << 16);
    o.z = bf16rne(a4) | (bf16rne(a5) << 16);
    o.w = bf16rne(a6) | (bf16rne(a7) << 16);
    // combine with this node's own x (sequential read) -> full-line writes
    const uint2* xb2 = (const uint2*)xb4;
    uint2 xp0 = xb2[(size_t)g * 32 + 2 * gl];
    uint2 xp1 = xb2[(size_t)g * 32 + 2 * gl + 1];
    ax4[(size_t)g * 32 + 2 * gl]     = make_uint4(o.x, o.y, xp0.x, xp0.y);
    ax4[(size_t)g * 32 + 2 * gl + 1] = make_uint4(o.z, o.w, xp1.x, xp1.y);
}

// ================= pass B: attention, ONE NODE PER 64-LANE WAVE.
// score = kq[g].xagg[c] (q eliminated algebraically). No-max softmax. =================

__global__ __launch_bounds__(256) void attn_k(const uint2* __restrict__ kq2,
                                              const uint4* __restrict__ ax4,
                                              const int* __restrict__ cur,
                                              const int* __restrict__ scol,
                                              uint2* __restrict__ xwb,
                                              float* __restrict__ sumw) {
    long g = (blockIdx.x * 256 + threadIdx.x) >> 6;  // node id (grid exact: 25000*4)
    int lane = threadIdx.x & 63;
    int l31 = lane & 31;
    int h = lane >> 5;  // half: edge parity
    int d = min(cur[g], CAP);
    uint2 ku = kq2[(size_t)g * 32 + l31];
    const float scale = 0.08838834764831845f;  // 1/sqrt(128)
    float k0 = bflo(ku.x) * scale, k1 = bfhi(ku.x) * scale;
    float k2 = bflo(ku.y) * scale, k3 = bfhi(ku.y) * scale;

    int cb = (lane < d) ? scol[(size_t)g * CAP + lane] : 0;  // whole bucket, one load
    float S = 0.f;
    float a0 = 0.f, a1 = 0.f, a2 = 0.f, a3 = 0.f;
    int k = 0;
    for (; k + 8 <= d; k += 8) {
        int c0 = __shfl(cb, k + h, 64);
        int c1 = __shfl(cb, k + 2 + h, 64);
        int c2 = __shfl(cb, k + 4 + h, 64);
        int c3 = __shfl(cb, k + 6 + h, 64);
        uint4 u0 = ax4[(size_t)c0 * 32 + l31];
        uint4 u1 = ax4[(size_t)c1 * 32 + l31];
        uint4 u2 = ax4[(size_t)c2 * 32 + l31];
        uint4 u3 = ax4[(size_t)c3 * 32 + l31];
        float p0 = k0 * bflo(u0.x) + k1 * bfhi(u0.x) + k2 * bflo(u0.y) + k3 * bfhi(u0.y);
        float p1 = k0 * bflo(u1.x) + k1 * bfhi(u1.x) + k2 * bflo(u1.y) + k3 * bfhi(u1.y);
        float p2 = k0 * bflo(u2.x) + k1 * bfhi(u2.x) + k2 * bflo(u2.y) + k3 * bfhi(u2.y);
        float p3 = k0 * bflo(u3.x) + k1 * bfhi(u3.x) + k2 * bflo(u3.y) + k3 * bfhi(u3.y);
#pragma unroll
        for (int off = 16; off > 0; off >>= 1) {
            p0 += __shfl_xor(p0, off, 32); p1 += __shfl_xor(p1, off, 32);
            p2 += __shfl_xor(p2, off, 32); p3 += __shfl_xor(p3, off, 32);
        }
        float e0 = __expf(p0), e1 = __expf(p1);
        float e2 = __expf(p2), e3 = __expf(p3);
        S += (e0 + e1) + (e2 + e3);
        a0 += e0 * bflo(u0.z) + e1 * bflo(u1.z) + e2 * bflo(u2.z) + e3 * bflo(u3.z);
        a1 += e0 * bfhi(u0.z) + e1 * bfhi(u1.z) + e2 * bfhi(u2.z) + e3 * bfhi(u3.z);
        a2 += e0 * bflo(u0.w) + e1 * bflo(u1.w) + e2 * bflo(u2.w) + e3 * bflo(u3.w);
        a3 += e0 * bfhi(u0.w) + e1 * bfhi(u1.w) + e2 * bfhi(u2.w) + e3 * bfhi(u3.w);
    }
    for (; k + 2 <= d; k += 2) {
        int c = __shfl(cb, k + h, 64);
        uint4 u = ax4[(size_t)c * 32 + l31];
        float p = k0 * bflo(u.x) + k1 * bfhi(u.x) + k2 * bflo(u.y) + k3 * bfhi(u.y);
#pragma unroll
        for (int off = 16; off > 0; off >>= 1) p += __shfl_xor(p, off, 32);
        float e0 = __expf(p);
        S += e0;
        a0 += e0 * bflo(u.z);
        a1 += e0 * bfhi(u.z);
        a2 += e0 * bflo(u.w);
        a3 += e0 * bfhi(u.w);
    }
    if (k < d) {  // last odd edge: both halves compute, half 0 accumulates
        int c = __shfl(cb, k, 64);
        uint4 u = ax4[(size_t)c * 32 + l31];
        float p = k0 * bflo(u.x) + k1 * bfhi(u.x) + k2 * bflo(u.y) + k3 * bfhi(u.y);
#pragma unroll
        for (int off = 16; off > 0; off >>= 1) p += __shfl_xor(p, off, 32);
        float e0 = __expf(p);
        if (h == 0) {
            S += e0;
            a0 += e0 * bflo(u.z);
            a1 += e0 * bfhi(u.z);
            a2 += e0 * bflo(u.w);
            a3 += e0 * bfhi(u.w);
        }
    }
    // combine the two halves
    S += __shfl_xor(S, 32, 64);
    a0 += __shfl_xor(a0, 32, 64);
    a1 += __shfl_xor(a1, 32, 64);
    a2 += __shfl_xor(a2, 32, 64);
    a3 += __shfl_xor(a3, 32, 64);
    float inv = 1.f / (S + 1e-8f);
    if (h == 0) {
        uint2 o;
        o.x = bf16rne(a0 * inv) | (bf16rne(a1 * inv) << 16);
        o.y = bf16rne(a2 * inv) | (bf16rne(a3 * inv) << 16);
        xwb[(size_t)g * 32 + l31] = o;
        if (l31 == 0) sumw[g] = S * inv;  // sum(alpha) for exact bias term
    }
}

// ================= final MFMA GEMM: out = lrelu(xw @ Wl + sumw*b), f32 out =================

__global__ __launch_bounds__(256) void fin_k(const ushort* __restrict__ Ab,
                                             const ushort* __restrict__ BTh,
                                             const ushort* __restrict__ BTl,
                                             const float* __restrict__ bl,
                                             const float* __restrict__ sumw,
                                             float* __restrict__ out) {
    int tid = threadIdx.x;
    int wave = tid >> 6, lane = tid & 63;
    int ln15 = lane & 15, quad = (lane >> 4) & 3;
    long base = (long)blockIdx.x * 128 + wave * 32;

    const bf16x8* A8 = (const bf16x8*)Ab;
    const bf16x8* Bh8 = (const bf16x8*)BTh;
    const bf16x8* Bl8 = (const bf16x8*)BTl;

    bf16x8 Af[2][4];
#pragma unroll
    for (int r = 0; r < 2; r++) {
        long row = base + r * 16 + ln15;
#pragma unroll
        for (int s = 0; s < 4; s++) Af[r][s] = A8[row * 16 + s * 4 + quad];
    }
    float blv[8];
#pragma unroll
    for (int t = 0; t < 8; t++) blv[t] = bl[t * 16 + ln15];

    f32x4 acc[2][8];
#pragma unroll
    for (int r = 0; r < 2; r++)
#pragma unroll
        for (int t = 0; t < 8; t++) acc[r][t] = (f32x4){0.f, 0.f, 0.f, 0.f};

#pragma unroll
    for (int phase = 0; phase < 2; phase++) {
        const bf16x8* B8 = phase ? Bl8 : Bh8;
#pragma unroll
        for (int s = 0; s < 4; s++) {
#pragma unroll
            for (int t = 0; t < 8; t++) {
                bf16x8 b = B8[(t * 16 + ln15) * 16 + s * 4 + quad];
                acc[0][t] = __builtin_amdgcn_mfma_f32_16x16x32_bf16(Af[0][s], b, acc[0][t], 0, 0, 0);
                acc[1][t] = __builtin_amdgcn_mfma_f32_16x16x32_bf16(Af[1][s], b, acc[1][t], 0, 0, 0);
            }
        }
    }
#pragma unroll
    for (int r = 0; r < 2; r++) {
#pragma unroll
        for (int reg = 0; reg < 4; reg++) {
            long node = base + r * 16 + quad * 4 + reg;
            if (node < N_NODES) {
                float sw = sumw[node];
#pragma unroll
                for (int t = 0; t < 8; t++) {
                    float v = acc[r][t][reg] + sw * blv[t];
                    v = v > 0.f ? v : 0.2f * v;
                    out[node * 128 + t * 16 + ln15] = v;
                }
            }
        }
    }
}

// ================= launch =================

extern "C" void kernel_launch(void* const* d_in, const int* in_sizes, int n_in,
                              void* d_out, int out_size, void* d_ws, size_t ws_size,
                              hipStream_t stream) {
    const float* x  = (const float*)d_in[0];
    const int* row  = (const int*)d_in[1];
    const int* col  = row + N_EDGES;
    const float* Wq = (const float*)d_in[2];
    const float* Wk = (const float*)d_in[3];
    // d_in[4] = W_v: unused
    const float* Wl = (const float*)d_in[5];
    const float* bl = (const float*)d_in[6];
    float* out = (float*)d_out;

    // workspace carve (~171 MB). fin_k A-loads overread <=96 rows past xwb
    // (lands in wbuf, valid memory).
    ushort* xb    = (ushort*)d_ws;                        // N*128 bf16 (25.6 MB)
    ushort* ax    = xb + (size_t)N_NODES * DIM;           // N*256 bf16 interleaved xagg|x (51.2 MB)
    ushort* kq    = ax + (size_t)N_NODES * 256;           // N*128 bf16 (25.6 MB)
    ushort* xwb   = kq + (size_t)N_NODES * DIM;           // 25.6 MB
    ushort* wbuf  = xwb + (size_t)N_NODES * DIM;          // 2*16384 bf16 (Wl split)
    ushort* WlTh = wbuf, *WlTl = wbuf + 16384;
    float* sumw = (float*)(wbuf + 2 * 16384);             // N f32
    int* cur  = (int*)(sumw + N_NODES);                   // N (degrees, by build_k)
    int* scol = cur + N_NODES;                            // N*CAP (25.6 MB)
    unsigned* bkt = (unsigned*)(scol + (size_t)N_NODES * CAP);  // 15.9 MB
    int* bktc = (int*)(bkt + (size_t)NB1 * GRID1 * SLOT1);      // 306 KB

    pb_k<<<1173, 256, 0, stream>>>(x, Wq, Wk, Wl, row, col, xb, kq,
                                   WlTh, WlTl, bkt, bktc);
    build_k<<<NB1, 1024, 0, stream>>>(bktc, bkt, cur, scol);
    xa_k<<<N_NODES / 16, 256, 0, stream>>>((const uint4*)xb, cur, scol, (uint4*)ax);
    attn_k<<<N_NODES / 4, 256, 0, stream>>>((const uint2*)kq, (const uint4*)ax,
                                            cur, scol, (uint2*)xwb, sumw);
    fin_k<<<(N_NODES + 127) / 128, 256, 0, stream>>>(xwb, WlTh, WlTl, bl, sumw, out);
}

// Round 11
// 439.408 us; speedup vs baseline: 1.0521x; 1.0246x over previous
//
#include <hip/hip_runtime.h>
#include <math.h>

#define N_NODES 100000
#define N_EDGES 1600000
#define DIM 128
#define CAP 64   // per-node edge bucket capacity; deg ~ Poisson(16), P(>64) ~ 1e-12

// two-phase binned scatter (no global atomics)
#define NB1 196      // bins of 512 nodes: bin = r >> 9
#define NPB 512      // nodes per bin
#define CHUNK1 4096  // edges per bin block
#define GRID1 391    // ceil(N_EDGES / CHUNK1)
#define SLOT1 52     // per-(bin,block) bucket cap; lambda=20.9 -> 6.8 sigma (passed r3-r10)
#define LSTRIDE 197  // LDS [p][bin] stride (odd -> conflict-free flush reads)

typedef short bf16x8 __attribute__((ext_vector_type(8)));
typedef float f32x4 __attribute__((ext_vector_type(4)));

// ---- bf16 helpers (RNE pack, cheap unpack) ----
static __device__ __forceinline__ unsigned bf16rne(float f) {
    unsigned u = __float_as_uint(f);
    return (u + 0x7FFFu + ((u >> 16) & 1u)) >> 16;
}
static __device__ __forceinline__ float bflo(unsigned u) { return __uint_as_float(u << 16); }
static __device__ __forceinline__ float bfhi(unsigned u) { return __uint_as_float(u & 0xFFFF0000u); }

// ================= pb: prep || bin in ONE dispatch.
// prep: xb = bf16(x); k_act = lrelu(x@Wk) (GEMM1, hi/lo);
//       kq = k_act @ Wq^T (GEMM2, hi/lo) -- score(g,c) = kq[g].xagg[c].
// bin: LDS-binned edge scatter, zero global atomics. =================

__global__ __launch_bounds__(256) void pb_k(
    const float* __restrict__ x, const float* __restrict__ Wq,
    const float* __restrict__ Wk, const float* __restrict__ Wl,
    const int* __restrict__ row, const int* __restrict__ col,
    ushort* __restrict__ xb, ushort* __restrict__ kq,
    ushort* __restrict__ WlTh, ushort* __restrict__ WlTl,
    unsigned* __restrict__ bkt, int* __restrict__ bktc) {
    __shared__ uint4 smem4[4352];  // 69632 B union: prep{b1,b2} | bin{lcnt,lbuf}
    int j = blockIdx.x, t = threadIdx.x;

    if (j % 3 == 2) {
        // ---------- bin role ----------
        int blk = j / 3;  // 0..390
        int* lcnt = (int*)smem4;
        unsigned* lbuf = (unsigned*)smem4 + 256;  // [p][bin], stride 197
        if (t < NB1) lcnt[t] = 0;
        __syncthreads();
        long base = (long)blk * CHUNK1;
        if (base + CHUNK1 <= N_EDGES) {
            const uint4* r4 = (const uint4*)row + (size_t)blk * 1024;
            const uint4* c4 = (const uint4*)col + (size_t)blk * 1024;
#pragma unroll
            for (int q = 0; q < 4; q++) {
                uint4 rv = r4[q * 256 + t];
                uint4 cv = c4[q * 256 + t];
                unsigned rr[4] = {rv.x, rv.y, rv.z, rv.w};
                unsigned cc[4] = {cv.x, cv.y, cv.z, cv.w};
#pragma unroll
                for (int i = 0; i < 4; i++) {
                    int b = rr[i] >> 9;
                    int p = atomicAdd(&lcnt[b], 1);
                    if (p < SLOT1) lbuf[p * LSTRIDE + b] = (cc[i] << 9) | (rr[i] & 511u);
                }
            }
        } else {
            for (int i = t; base + i < N_EDGES; i += 256) {
                unsigned r = (unsigned)row[base + i], c = (unsigned)col[base + i];
                int b = r >> 9;
                int p = atomicAdd(&lcnt[b], 1);
                if (p < SLOT1) lbuf[p * LSTRIDE + b] = (c << 9) | (r & 511u);
            }
        }
        __syncthreads();
        if (t < NB1) bktc[(size_t)blk * NB1 + t] = min(lcnt[t], SLOT1);
        int wave = t >> 6, lane = t & 63;
        for (int s = wave; s < NB1; s += 4) {
            if (lane < min(lcnt[s], SLOT1))
                bkt[((size_t)s * GRID1 + blk) * SLOT1 + lane] = lbuf[lane * LSTRIDE + s];
        }
        return;
    }

    // ---------- prep role ----------
    int p = (j / 3) * 2 + (j % 3);  // 0..781
    ushort* b1 = (ushort*)smem4;    // 128x136: k_act staging (GEMM2 A)
    ushort* b2 = b1 + 17408;        // 128x136: W staging (hi then lo, Wk then Wq)

    if (p == 0) {
        // Wl split for fin (transposed layout [out][in])
        for (int i = t; i < 16384; i += 256) {
            int k = i >> 7, n = i & 127;
            float v = Wl[i];
            unsigned hi = bf16rne(v);
            WlTh[n * 128 + k] = (ushort)hi;
            WlTl[n * 128 + k] = (ushort)bf16rne(v - bflo(hi));
        }
    }
    // stage Wk hi (transposed: [out n][in k])
    for (int i = t; i < 16384; i += 256) {
        int k = i >> 7, n = i & 127;
        b2[n * 136 + k] = (ushort)bf16rne(Wk[i]);
    }

    int wave = t >> 6, lane = t & 63;
    int ln15 = lane & 15, quad = lane >> 4;
    long base = (long)p * 128 + wave * 32;

    bf16x8 Af[2][4];
#pragma unroll
    for (int r = 0; r < 2; r++) {
        long rw = base + r * 16 + ln15;
        long rowc = rw < N_NODES ? rw : N_NODES - 1;
#pragma unroll
        for (int s = 0; s < 4; s++) {
            int ch = s * 4 + quad;  // 8-feat chunk index (0..15)
            const float4* xp = (const float4*)(x + rowc * 128 + ch * 8);
            float4 u0 = xp[0], u1 = xp[1];
            bf16x8 f;
            f[0] = (short)bf16rne(u0.x); f[1] = (short)bf16rne(u0.y);
            f[2] = (short)bf16rne(u0.z); f[3] = (short)bf16rne(u0.w);
            f[4] = (short)bf16rne(u1.x); f[5] = (short)bf16rne(u1.y);
            f[6] = (short)bf16rne(u1.z); f[7] = (short)bf16rne(u1.w);
            Af[r][s] = f;
            if (rw < N_NODES) *(bf16x8*)(xb + rw * 128 + ch * 8) = f;
        }
    }
    f32x4 acc[2][8];
#pragma unroll
    for (int r = 0; r < 2; r++)
#pragma unroll
        for (int t8 = 0; t8 < 8; t8++) acc[r][t8] = (f32x4){0.f, 0.f, 0.f, 0.f};

    __syncthreads();
    // GEMM1 hi
#pragma unroll
    for (int s = 0; s < 4; s++) {
#pragma unroll
        for (int t8 = 0; t8 < 8; t8++) {
            bf16x8 b = *(const bf16x8*)(b2 + (t8 * 16 + ln15) * 136 + (s * 4 + quad) * 8);
            acc[0][t8] = __builtin_amdgcn_mfma_f32_16x16x32_bf16(Af[0][s], b, acc[0][t8], 0, 0, 0);
            acc[1][t8] = __builtin_amdgcn_mfma_f32_16x16x32_bf16(Af[1][s], b, acc[1][t8], 0, 0, 0);
        }
    }
    __syncthreads();
    // restage Wk lo
    for (int i = t; i < 16384; i += 256) {
        int k = i >> 7, n = i & 127;
        float v = Wk[i];
        unsigned hi = bf16rne(v);
        b2[n * 136 + k] = (ushort)bf16rne(v - bflo(hi));
    }
    __syncthreads();
    // GEMM1 lo
#pragma unroll
    for (int s = 0; s < 4; s++) {
#pragma unroll
        for (int t8 = 0; t8 < 8; t8++) {
            bf16x8 b = *(const bf16x8*)(b2 + (t8 * 16 + ln15) * 136 + (s * 4 + quad) * 8);
            acc[0][t8] = __builtin_amdgcn_mfma_f32_16x16x32_bf16(Af[0][s], b, acc[0][t8], 0, 0, 0);
            acc[1][t8] = __builtin_amdgcn_mfma_f32_16x16x32_bf16(Af[1][s], b, acc[1][t8], 0, 0, 0);
        }
    }
    // k_act = lrelu(acc) -> b1 (bf16, [local node][feat])
#pragma unroll
    for (int r = 0; r < 2; r++) {
#pragma unroll
        for (int reg = 0; reg < 4; reg++) {
            int rl = wave * 32 + r * 16 + quad * 4 + reg;  // 0..127
#pragma unroll
            for (int t8 = 0; t8 < 8; t8++) {
                float v = acc[r][t8][reg];
                v = v > 0.f ? v : 0.2f * v;
                b1[rl * 136 + t8 * 16 + ln15] = (ushort)bf16rne(v);
            }
        }
    }
    __syncthreads();
    // stage Wq hi DIRECT order: B-layout [out j][in f] = Wq[j*128+f] (no transpose)
    for (int i = t; i < 16384; i += 256) {
        b2[(i >> 7) * 136 + (i & 127)] = (ushort)bf16rne(Wq[i]);
    }
    __syncthreads();
#pragma unroll
    for (int r = 0; r < 2; r++)
#pragma unroll
        for (int t8 = 0; t8 < 8; t8++) acc[r][t8] = (f32x4){0.f, 0.f, 0.f, 0.f};
    // GEMM2 hi: kq = k_act @ Wq^T
#pragma unroll
    for (int r = 0; r < 2; r++) {
        bf16x8 af[4];
#pragma unroll
        for (int s = 0; s < 4; s++)
            af[s] = *(const bf16x8*)(b1 + (wave * 32 + r * 16 + ln15) * 136 + (s * 4 + quad) * 8);
#pragma unroll
        for (int s = 0; s < 4; s++) {
#pragma unroll
            for (int t8 = 0; t8 < 8; t8++) {
                bf16x8 b = *(const bf16x8*)(b2 + (t8 * 16 + ln15) * 136 + (s * 4 + quad) * 8);
                acc[r][t8] = __builtin_amdgcn_mfma_f32_16x16x32_bf16(af[s], b, acc[r][t8], 0, 0, 0);
            }
        }
    }
    __syncthreads();
    // restage Wq lo
    for (int i = t; i < 16384; i += 256) {
        float v = Wq[i];
        unsigned hi = bf16rne(v);
        b2[(i >> 7) * 136 + (i & 127)] = (ushort)bf16rne(v - bflo(hi));
    }
    __syncthreads();
    // GEMM2 lo
#pragma unroll
    for (int r = 0; r < 2; r++) {
        bf16x8 af[4];
#pragma unroll
        for (int s = 0; s < 4; s++)
            af[s] = *(const bf16x8*)(b1 + (wave * 32 + r * 16 + ln15) * 136 + (s * 4 + quad) * 8);
#pragma unroll
        for (int s = 0; s < 4; s++) {
#pragma unroll
            for (int t8 = 0; t8 < 8; t8++) {
                bf16x8 b = *(const bf16x8*)(b2 + (t8 * 16 + ln15) * 136 + (s * 4 + quad) * 8);
                acc[r][t8] = __builtin_amdgcn_mfma_f32_16x16x32_bf16(af[s], b, acc[r][t8], 0, 0, 0);
            }
        }
    }
    // store kq
#pragma unroll
    for (int r = 0; r < 2; r++) {
#pragma unroll
        for (int reg = 0; reg < 4; reg++) {
            long node = base + r * 16 + quad * 4 + reg;
            if (node < N_NODES) {
#pragma unroll
                for (int t8 = 0; t8 < 8; t8++)
                    kq[node * 128 + t8 * 16 + ln15] = (ushort)bf16rne(acc[r][t8][reg]);
            }
        }
    }
}

// ================= bxa: fused build + xagg. One block per HALF-bin (256 nodes,
// 392 blocks, 1024 thr, 64KB LDS buckets -> 2 blocks/CU). Scatter into LDS,
// coalesced scol dump, degrees, then gather xagg reading indices from LDS
// (broadcast int4 reads, no scol round-trip, no trailing barrier). =================

__global__ __launch_bounds__(1024) void bxa_k(const int* __restrict__ bktc,
                                              const unsigned* __restrict__ bkt,
                                              const uint4* __restrict__ xb4,
                                              int* __restrict__ cur,
                                              int* __restrict__ scol,
                                              uint4* __restrict__ ax4) {
    __shared__ int lcnt[256];
    __shared__ int lbkt[256 * CAP];  // 64 KB
    __shared__ int lc[GRID1];
    int blk = blockIdx.x;  // 0..391
    int b = blk >> 1, half = blk & 1;
    int t = threadIdx.x;
    if (t < 256) lcnt[t] = 0;
    if (t < GRID1) lc[t] = bktc[(size_t)t * NB1 + b];
    __syncthreads();
    int wave = t >> 6, lane = t & 63;
    const unsigned* D = bkt + (size_t)b * GRID1 * SLOT1;
    int hbase = half << 8;
    for (int s = wave; s < GRID1; s += 16) {
        if (lane < lc[s]) {
            unsigned v = D[(size_t)s * SLOT1 + lane];
            int rl = (int)(v & 511u) - hbase;
            if ((unsigned)rl < 256u) {
                int p = atomicAdd(&lcnt[rl], 1);
                if (p < CAP) lbkt[rl * CAP + p] = (int)(v >> 9);
            }
        }
    }
    __syncthreads();
    long nbase = (long)b * NPB + hbase;
    int nv = (int)((long)N_NODES - nbase);  // valid nodes in this half
    if (nv > 256) nv = 256;
    if (nv < 0) nv = 0;
    if (t < nv) cur[nbase + t] = min(lcnt[t], CAP);
    // coalesced scol dump from LDS (full CAP rows; tails beyond deg unread)
    {
        const uint4* lb4 = (const uint4*)lbkt;
        uint4* sc4 = (uint4*)(scol + nbase * CAP);
        int qn = nv * (CAP / 4);
        for (int i = t; i < qn; i += 1024) sc4[i] = lb4[i];
    }
    // gather phase: 64 groups x 16 lanes; 4 nodes per group (sum-balanced, no barrier)
    int grp = t >> 4, gl = t & 15;
    const uint2* xb2 = (const uint2*)xb4;
#pragma unroll
    for (int i = 0; i < 4; i++) {
        int rl = grp * 4 + i;
        if (rl >= nv) continue;
        long node = nbase + rl;
        int d = min(lcnt[rl], CAP);
        const int* L = &lbkt[rl * CAP];
        float a0 = 0.f, a1 = 0.f, a2 = 0.f, a3 = 0.f;
        float a4 = 0.f, a5 = 0.f, a6 = 0.f, a7 = 0.f;
        int k = 0;
        for (; k + 4 <= d; k += 4) {
            int4 cc = *(const int4*)(L + k);  // LDS broadcast within 16-lane group
            uint4 u0 = xb4[(size_t)cc.x * 16 + gl];
            uint4 u1 = xb4[(size_t)cc.y * 16 + gl];
            uint4 u2 = xb4[(size_t)cc.z * 16 + gl];
            uint4 u3 = xb4[(size_t)cc.w * 16 + gl];
            a0 += bflo(u0.x); a1 += bfhi(u0.x); a2 += bflo(u0.y); a3 += bfhi(u0.y);
            a4 += bflo(u0.z); a5 += bfhi(u0.z); a6 += bflo(u0.w); a7 += bfhi(u0.w);
            a0 += bflo(u1.x); a1 += bfhi(u1.x); a2 += bflo(u1.y); a3 += bfhi(u1.y);
            a4 += bflo(u1.z); a5 += bfhi(u1.z); a6 += bflo(u1.w); a7 += bfhi(u1.w);
            a0 += bflo(u2.x); a1 += bfhi(u2.x); a2 += bflo(u2.y); a3 += bfhi(u2.y);
            a4 += bflo(u2.z); a5 += bfhi(u2.z); a6 += bflo(u2.w); a7 += bfhi(u2.w);
            a0 += bflo(u3.x); a1 += bfhi(u3.x); a2 += bflo(u3.y); a3 += bfhi(u3.y);
            a4 += bflo(u3.z); a5 += bfhi(u3.z); a6 += bflo(u3.w); a7 += bfhi(u3.w);
        }
        for (; k < d; k++) {
            int c = L[k];
            uint4 u = xb4[(size_t)c * 16 + gl];
            a0 += bflo(u.x); a1 += bfhi(u.x); a2 += bflo(u.y); a3 += bfhi(u.y);
            a4 += bflo(u.z); a5 += bfhi(u.z); a6 += bflo(u.w); a7 += bfhi(u.w);
        }
        uint4 o;
        o.x = bf16rne(a0) | (bf16rne(a1) << 16);
        o.y = bf16rne(a2) | (bf16rne(a3) << 16);
        o.z = bf16rne(a4) | (bf16rne(a5) << 16);
        o.w = bf16rne(a6) | (bf16rne(a7) << 16);
        // combine with node's own x -> full-line ax writes
        uint2 xp0 = xb2[(size_t)node * 32 + 2 * gl];
        uint2 xp1 = xb2[(size_t)node * 32 + 2 * gl + 1];
        ax4[(size_t)node * 32 + 2 * gl]     = make_uint4(o.x, o.y, xp0.x, xp0.y);
        ax4[(size_t)node * 32 + 2 * gl + 1] = make_uint4(o.z, o.w, xp1.x, xp1.y);
    }
}

// ================= pass B: attention, ONE NODE PER 64-LANE WAVE.
// score = kq[g].xagg[c] (q eliminated algebraically). No-max softmax. =================

__global__ __launch_bounds__(256) void attn_k(const uint2* __restrict__ kq2,
                                              const uint4* __restrict__ ax4,
                                              const int* __restrict__ cur,
                                              const int* __restrict__ scol,
                                              uint2* __restrict__ xwb,
                                              float* __restrict__ sumw) {
    long g = (blockIdx.x * 256 + threadIdx.x) >> 6;  // node id (grid exact: 25000*4)
    int lane = threadIdx.x & 63;
    int l31 = lane & 31;
    int h = lane >> 5;  // half: edge parity
    int d = min(cur[g], CAP);
    uint2 ku = kq2[(size_t)g * 32 + l31];
    const float scale = 0.08838834764831845f;  // 1/sqrt(128)
    float k0 = bflo(ku.x) * scale, k1 = bfhi(ku.x) * scale;
    float k2 = bflo(ku.y) * scale, k3 = bfhi(ku.y) * scale;

    int cb = (lane < d) ? scol[(size_t)g * CAP + lane] : 0;  // whole bucket, one load
    float S = 0.f;
    float a0 = 0.f, a1 = 0.f, a2 = 0.f, a3 = 0.f;
    int k = 0;
    for (; k + 8 <= d; k += 8) {
        int c0 = __shfl(cb, k + h, 64);
        int c1 = __shfl(cb, k + 2 + h, 64);
        int c2 = __shfl(cb, k + 4 + h, 64);
        int c3 = __shfl(cb, k + 6 + h, 64);
        uint4 u0 = ax4[(size_t)c0 * 32 + l31];
        uint4 u1 = ax4[(size_t)c1 * 32 + l31];
        uint4 u2 = ax4[(size_t)c2 * 32 + l31];
        uint4 u3 = ax4[(size_t)c3 * 32 + l31];
        float p0 = k0 * bflo(u0.x) + k1 * bfhi(u0.x) + k2 * bflo(u0.y) + k3 * bfhi(u0.y);
        float p1 = k0 * bflo(u1.x) + k1 * bfhi(u1.x) + k2 * bflo(u1.y) + k3 * bfhi(u1.y);
        float p2 = k0 * bflo(u2.x) + k1 * bfhi(u2.x) + k2 * bflo(u2.y) + k3 * bfhi(u2.y);
        float p3 = k0 * bflo(u3.x) + k1 * bfhi(u3.x) + k2 * bflo(u3.y) + k3 * bfhi(u3.y);
#pragma unroll
        for (int off = 16; off > 0; off >>= 1) {
            p0 += __shfl_xor(p0, off, 32); p1 += __shfl_xor(p1, off, 32);
            p2 += __shfl_xor(p2, off, 32); p3 += __shfl_xor(p3, off, 32);
        }
        float e0 = __expf(p0), e1 = __expf(p1);
        float e2 = __expf(p2), e3 = __expf(p3);
        S += (e0 + e1) + (e2 + e3);
        a0 += e0 * bflo(u0.z) + e1 * bflo(u1.z) + e2 * bflo(u2.z) + e3 * bflo(u3.z);
        a1 += e0 * bfhi(u0.z) + e1 * bfhi(u1.z) + e2 * bfhi(u2.z) + e3 * bfhi(u3.z);
        a2 += e0 * bflo(u0.w) + e1 * bflo(u1.w) + e2 * bflo(u2.w) + e3 * bflo(u3.w);
        a3 += e0 * bfhi(u0.w) + e1 * bfhi(u1.w) + e2 * bfhi(u2.w) + e3 * bfhi(u3.w);
    }
    for (; k + 2 <= d; k += 2) {
        int c = __shfl(cb, k + h, 64);
        uint4 u = ax4[(size_t)c * 32 + l31];
        float p = k0 * bflo(u.x) + k1 * bfhi(u.x) + k2 * bflo(u.y) + k3 * bfhi(u.y);
#pragma unroll
        for (int off = 16; off > 0; off >>= 1) p += __shfl_xor(p, off, 32);
        float e0 = __expf(p);
        S += e0;
        a0 += e0 * bflo(u.z);
        a1 += e0 * bfhi(u.z);
        a2 += e0 * bflo(u.w);
        a3 += e0 * bfhi(u.w);
    }
    if (k < d) {  // last odd edge: both halves compute, half 0 accumulates
        int c = __shfl(cb, k, 64);
        uint4 u = ax4[(size_t)c * 32 + l31];
        float p = k0 * bflo(u.x) + k1 * bfhi(u.x) + k2 * bflo(u.y) + k3 * bfhi(u.y);
#pragma unroll
        for (int off = 16; off > 0; off >>= 1) p += __shfl_xor(p, off, 32);
        float e0 = __expf(p);
        if (h == 0) {
            S += e0;
            a0 += e0 * bflo(u.z);
            a1 += e0 * bfhi(u.z);
            a2 += e0 * bflo(u.w);
            a3 += e0 * bfhi(u.w);
        }
    }
    // combine the two halves
    S += __shfl_xor(S, 32, 64);
    a0 += __shfl_xor(a0, 32, 64);
    a1 += __shfl_xor(a1, 32, 64);
    a2 += __shfl_xor(a2, 32, 64);
    a3 += __shfl_xor(a3, 32, 64);
    float inv = 1.f / (S + 1e-8f);
    if (h == 0) {
        uint2 o;
        o.x = bf16rne(a0 * inv) | (bf16rne(a1 * inv) << 16);
        o.y = bf16rne(a2 * inv) | (bf16rne(a3 * inv) << 16);
        xwb[(size_t)g * 32 + l31] = o;
        if (l31 == 0) sumw[g] = S * inv;  // sum(alpha) for exact bias term
    }
}

// ================= final MFMA GEMM: out = lrelu(xw @ Wl + sumw*b), f32 out =================

__global__ __launch_bounds__(256) void fin_k(const ushort* __restrict__ Ab,
                                             const ushort* __restrict__ BTh,
                                             const ushort* __restrict__ BTl,
                                             const float* __restrict__ bl,
                                             const float* __restrict__ sumw,
                                             float* __restrict__ out) {
    int tid = threadIdx.x;
    int wave = tid >> 6, lane = tid & 63;
    int ln15 = lane & 15, quad = (lane >> 4) & 3;
    long base = (long)blockIdx.x * 128 + wave * 32;

    const bf16x8* A8 = (const bf16x8*)Ab;
    const bf16x8* Bh8 = (const bf16x8*)BTh;
    const bf16x8* Bl8 = (const bf16x8*)BTl;

    bf16x8 Af[2][4];
#pragma unroll
    for (int r = 0; r < 2; r++) {
        long row = base + r * 16 + ln15;
#pragma unroll
        for (int s = 0; s < 4; s++) Af[r][s] = A8[row * 16 + s * 4 + quad];
    }
    float blv[8];
#pragma unroll
    for (int t = 0; t < 8; t++) blv[t] = bl[t * 16 + ln15];

    f32x4 acc[2][8];
#pragma unroll
    for (int r = 0; r < 2; r++)
#pragma unroll
        for (int t = 0; t < 8; t++) acc[r][t] = (f32x4){0.f, 0.f, 0.f, 0.f};

#pragma unroll
    for (int phase = 0; phase < 2; phase++) {
        const bf16x8* B8 = phase ? Bl8 : Bh8;
#pragma unroll
        for (int s = 0; s < 4; s++) {
#pragma unroll
            for (int t = 0; t < 8; t++) {
                bf16x8 b = B8[(t * 16 + ln15) * 16 + s * 4 + quad];
                acc[0][t] = __builtin_amdgcn_mfma_f32_16x16x32_bf16(Af[0][s], b, acc[0][t], 0, 0, 0);
                acc[1][t] = __builtin_amdgcn_mfma_f32_16x16x32_bf16(Af[1][s], b, acc[1][t], 0, 0, 0);
            }
        }
    }
#pragma unroll
    for (int r = 0; r < 2; r++) {
#pragma unroll
        for (int reg = 0; reg < 4; reg++) {
            long node = base + r * 16 + quad * 4 + reg;
            if (node < N_NODES) {
                float sw = sumw[node];
#pragma unroll
                for (int t = 0; t < 8; t++) {
                    float v = acc[r][t][reg] + sw * blv[t];
                    v = v > 0.f ? v : 0.2f * v;
                    out[node * 128 + t * 16 + ln15] = v;
                }
            }
        }
    }
}

// ================= launch =================

extern "C" void kernel_launch(void* const* d_in, const int* in_sizes, int n_in,
                              void* d_out, int out_size, void* d_ws, size_t ws_size,
                              hipStream_t stream) {
    const float* x  = (const float*)d_in[0];
    const int* row  = (const int*)d_in[1];
    const int* col  = row + N_EDGES;
    const float* Wq = (const float*)d_in[2];
    const float* Wk = (const float*)d_in[3];
    // d_in[4] = W_v: unused
    const float* Wl = (const float*)d_in[5];
    const float* bl = (const float*)d_in[6];
    float* out = (float*)d_out;

    // workspace carve (~171 MB). fin_k A-loads overread <=96 rows past xwb
    // (lands in wbuf, valid memory).
    ushort* xb    = (ushort*)d_ws;                        // N*128 bf16 (25.6 MB)
    ushort* ax    = xb + (size_t)N_NODES * DIM;           // N*256 bf16 interleaved xagg|x (51.2 MB)
    ushort* kq    = ax + (size_t)N_NODES * 256;           // N*128 bf16 (25.6 MB)
    ushort* xwb   = kq + (size_t)N_NODES * DIM;           // 25.6 MB
    ushort* wbuf  = xwb + (size_t)N_NODES * DIM;          // 2*16384 bf16 (Wl split)
    ushort* WlTh = wbuf, *WlTl = wbuf + 16384;
    float* sumw = (float*)(wbuf + 2 * 16384);             // N f32
    int* cur  = (int*)(sumw + N_NODES);                   // N (degrees, by bxa_k)
    int* scol = cur + N_NODES;                            // N*CAP (25.6 MB)
    unsigned* bkt = (unsigned*)(scol + (size_t)N_NODES * CAP);  // 15.9 MB
    int* bktc = (int*)(bkt + (size_t)NB1 * GRID1 * SLOT1);      // 306 KB

    pb_k<<<1173, 256, 0, stream>>>(x, Wq, Wk, Wl, row, col, xb, kq,
                                   WlTh, WlTl, bkt, bktc);
    bxa_k<<<NB1 * 2, 1024, 0, stream>>>(bktc, bkt, (const uint4*)xb, cur, scol,
                                        (uint4*)ax);
    attn_k<<<N_NODES / 4, 256, 0, stream>>>((const uint2*)kq, (const uint4*)ax,
                                            cur, scol, (uint2*)xwb, sumw);
    fin_k<<<(N_NODES + 127) / 128, 256, 0, stream>>>(xwb, WlTh, WlTl, bl, sumw, out);
}